// Round 1
// baseline (578.180 us; speedup 1.0000x reference)
//
#include <hip/hip_runtime.h>
#include <hip/hip_bf16.h>

// ---------------------------------------------------------------------------
// Bahdanau attention, fused flash-style.  B=64, S=2048, E=D=U=512.
//  K1: pack W1 (fp32) -> bf16 in MFMA B-fragment order (ws)
//  K2: c[b,u] = H@W2 + b1 + b2   (fp32, ws)
//  K3: scores_ctx: per (b, 128-row strip), 8 waves x 16 rows:
//        afrag = 16 rows x K=512 bf16 in 64 VGPRs.
//        __launch_bounds__(512,2): cap 256 regs -> arch ~128 (R4: (x,3)
//        halves arch cap to ~85 and spills). 120 VGPR + 8 acc = 128 total
//        -> 4 waves/SIMD -> 2 blocks/CU = 16 waves/CU (~50% occ, was 23%).
//        B 16KB tiles DMA double-buffered in LDS; each tile+barrier now
//        amortized over 128 rows (was 64) -> half the DMA + barrier/row.
//        score s = tanh(EO@W1 + c)·V ; strip m,l ; partial ctx from afrag
//  K4: combine 16 strips: M,L per b; context; weights = exp(s-M)/L.
// d_out layout: context [64*512] then weights [64*2048].
// ws: W1p 512K | cvec 128K | m 8K | l 8K | ck 4M   (~4.7 MB)
// ---------------------------------------------------------------------------

typedef __attribute__((ext_vector_type(8))) short bf16x8;   // 8 bf16 = 4 VGPR
typedef __attribute__((ext_vector_type(4))) float f32x4;

#define NB 64
#define NS 2048
#define NE 512
#define NU 512
#define NSTRIP 16   // strips per batch
#define SROWS 128   // rows per strip

// async 16B/lane global->LDS DMA: lds dest = wave-uniform base + lane*16
#define ASYNC_CP16(gsrc, ldst)                                               \
  __builtin_amdgcn_global_load_lds(                                          \
      (const __attribute__((address_space(1))) unsigned int*)(gsrc),         \
      (__attribute__((address_space(3))) unsigned int*)(ldst), 16, 0, 0)

__device__ __forceinline__ unsigned short f2bf(float f) {
  union { float f; unsigned int u; } x; x.f = f;
  unsigned int u = x.u;
  unsigned int r = (u + 0x7fffu + ((u >> 16) & 1u)) >> 16;  // RNE
  return (unsigned short)r;
}

__device__ __forceinline__ float bf2f(short s) {
  union { unsigned int u; float f; } x;
  x.u = ((unsigned int)(unsigned short)s) << 16;
  return x.f;
}

__device__ __forceinline__ float tanh_fast(float x) {
  x = fminf(fmaxf(x, -15.f), 15.f);
  float e = __expf(2.f * x);
  return 1.f - 2.f / (e + 1.f);
}

// --- K1: pack W1[k][n] (fp32 512x512) -> bf16 MFMA B-frag order:
//     W1p[(((nt*16+kt)*64 + lane)*8 + j)] = bf16(W1[kt*32+(lane>>4)*8+j][nt*16+(lane&15)])
__global__ __launch_bounds__(256) void pack_w1_kernel(
    const float* __restrict__ W1, unsigned short* __restrict__ W1p) {
  int t = blockIdx.x * 256 + threadIdx.x;
  int k = t >> 9, n = t & 511;
  int kt = k >> 5, kr = k & 31;
  int quad = kr >> 3, j = kr & 7;
  int l = (quad << 4) | (n & 15);
  int nt = n >> 4;
  int dst = ((((nt << 4) + kt) * 64 + l) << 3) + j;
  W1p[dst] = f2bf(W1[t]);
}

// --- K2: c[b][u] = sum_d H[b][d]*W2[d][u] + b1[u] + b2[u]
__global__ __launch_bounds__(512) void compute_c_kernel(
    const float* __restrict__ H, const float* __restrict__ W2,
    const float* __restrict__ b1, const float* __restrict__ b2,
    float* __restrict__ cvec) {
  const int b = blockIdx.x, u = threadIdx.x;
  __shared__ float hs[512];
  hs[u] = H[(b << 9) + u];
  __syncthreads();
  float s = 0.f;
#pragma unroll 8
  for (int d = 0; d < 512; d++) s = fmaf(hs[d], W2[(d << 9) + u], s);
  cvec[(b << 9) + u] = s + b1[u] + b2[u];
}

// --- K3: scores + softmax partials + context partials.
// grid 1024 (= 64 b * 16 strips of 128 rows), 512 thr (8 waves x 16 rows).
__global__ __launch_bounds__(512, 2) void scores_ctx_kernel(
    const float* __restrict__ EO, const unsigned short* __restrict__ W1p,
    const float* __restrict__ cvec, const float* __restrict__ V,
    float* __restrict__ scores, float* __restrict__ m_ws,
    float* __restrict__ l_ws, float* __restrict__ ck_ws) {
  __shared__ __align__(16) unsigned short Bs[2][8192];  // 2 x 16KB (1 nt tile)
  __shared__ float cs[512], vs[512];
  __shared__ float sc_l[SROWS], p_l[SROWS];
  __shared__ __align__(16) float cpart[8][512];

  const int tid = threadIdx.x;
  const int b = blockIdx.x >> 4;
  const int strip = blockIdx.x & 15;
  const int s0 = strip << 7;   // *128
  const int lane = tid & 63, wave = tid >> 6;
  const int quad = lane >> 4, col = lane & 15;

  const uint4* W1p4 = (const uint4*)W1p;  // one 16KB tile = 1024 uint4

  // ---- kick off DMA of B tile 0 (nt=0); 1024 uint4 = 2 x 512 lanes
#pragma unroll
  for (int i = 0; i < 2; i++)
    ASYNC_CP16(W1p4 + i * 512 + wave * 64 + lane,
               ((char*)&Bs[0][0]) + (i * 512 + wave * 64) * 16);

  cs[tid] = cvec[(b << 9) + tid];
  vs[tid] = V[tid];

  // ---- A-fragments straight from global: 16 rows x K=512, fp32 -> bf16.
  //      Lane (quad,col) holds row col, k = kt*32 + quad*8 + j.  64 VGPRs.
  bf16x8 afrag[16];
  {
    const float* rp =
        EO + ((size_t)(b * NS + s0 + wave * 16 + col)) * NE + quad * 8;
#pragma unroll
    for (int kt = 0; kt < 16; kt++) {
      float4 x = *(const float4*)(rp + kt * 32);
      float4 y = *(const float4*)(rp + kt * 32 + 4);
      union { short s[8]; bf16x8 v; } u0;
      u0.s[0] = (short)f2bf(x.x); u0.s[1] = (short)f2bf(x.y);
      u0.s[2] = (short)f2bf(x.z); u0.s[3] = (short)f2bf(x.w);
      u0.s[4] = (short)f2bf(y.x); u0.s[5] = (short)f2bf(y.y);
      u0.s[6] = (short)f2bf(y.z); u0.s[7] = (short)f2bf(y.w);
      afrag[kt] = u0.v;
    }
  }

  __syncthreads();  // drains DMA vmcnt -> tile 0 ready

  float sacc[4] = {0.f, 0.f, 0.f, 0.f};

  for (int nt = 0; nt < 32; nt++) {
    const int cur = nt & 1;
    // DMA-prefetch next 16KB B tile into the other buffer (overlaps MFMAs)
    if (nt < 31) {
#pragma unroll
      for (int i = 0; i < 2; i++)
        ASYNC_CP16(W1p4 + (nt + 1) * 1024 + i * 512 + wave * 64 + lane,
                   ((char*)&Bs[cur ^ 1][0]) + (i * 512 + wave * 64) * 16);
    }
    f32x4 acc = {0.f, 0.f, 0.f, 0.f};
    const bf16x8* bp = (const bf16x8*)&Bs[cur][0];
#pragma unroll
    for (int kt = 0; kt < 16; kt++) {
      bf16x8 bfr = bp[kt * 64 + lane];
      acc = __builtin_amdgcn_mfma_f32_16x16x32_bf16(afrag[kt], bfr, acc, 0, 0, 0);
    }
    // fused epilogue: score partial += tanh(acc + c[u]) * V[u]
    int u = (nt << 4) + col;
    float cu = cs[u], vu = vs[u];
#pragma unroll
    for (int r = 0; r < 4; r++)
      sacc[r] += tanh_fast(acc[r] + cu) * vu;
    __syncthreads();  // all reads of cur done + next tile's DMA drained
  }

  // ---- reduce scores over the 16 col-lanes of each quad-group
#pragma unroll
  for (int m = 1; m < 16; m <<= 1)
#pragma unroll
    for (int r = 0; r < 4; r++)
      sacc[r] += __shfl_xor(sacc[r], m, 64);

  if (col == 0) {
#pragma unroll
    for (int r = 0; r < 4; r++) {
      int row = wave * 16 + quad * 4 + r;   // C/D: row = quad*4 + reg
      sc_l[row] = sacc[r];
      scores[(size_t)b * NS + s0 + row] = sacc[r];  // raw scores
    }
  }
  __syncthreads();

  // ---- strip max + l over the 128 rows (wave 0, 2 rows/lane)
  if (wave == 0) {
    float a0 = sc_l[lane], a1 = sc_l[lane + 64];
    float m0 = fmaxf(a0, a1);
#pragma unroll
    for (int off = 32; off; off >>= 1) m0 = fmaxf(m0, __shfl_xor(m0, off, 64));
    float e0 = __expf(a0 - m0), e1 = __expf(a1 - m0);
    p_l[lane] = e0; p_l[lane + 64] = e1;
    float p = e0 + e1;
#pragma unroll
    for (int off = 32; off; off >>= 1) p += __shfl_xor(p, off, 64);
    if (lane == 0) {
      m_ws[b * NSTRIP + strip] = m0;
      l_ws[b * NSTRIP + strip] = p;
    }
  }
  __syncthreads();

  // ---- context partials from register-resident bf16 EO fragments.
  // lane holds row (wave*16 + col), e = kt*32 + quad*8 + j.
  const float p0 = p_l[wave * 16 + col];
#pragma unroll
  for (int kt = 0; kt < 16; kt++) {
    float v[8];
#pragma unroll
    for (int j = 0; j < 8; j++) v[j] = p0 * bf2f(afrag[kt][j]);
#pragma unroll
    for (int m = 1; m < 16; m <<= 1)
#pragma unroll
      for (int j = 0; j < 8; j++) v[j] += __shfl_xor(v[j], m, 64);
    if (col == 0) {
      float* dst = &cpart[wave][kt * 32 + quad * 8];
      *(float4*)dst = make_float4(v[0], v[1], v[2], v[3]);
      *(float4*)(dst + 4) = make_float4(v[4], v[5], v[6], v[7]);
    }
  }
  __syncthreads();

  // ---- fold 8 wave-partials, write strip context partial to ws
  {
    float s = 0.f;
#pragma unroll
    for (int w = 0; w < 8; w++) s += cpart[w][tid];
    ck_ws[((size_t)(b * NSTRIP + strip)) * 512 + tid] = s;
  }
}

// --- K4: combine 16 strips: context + normalized weights.  64 blocks x 256.
__global__ __launch_bounds__(256) void combine_kernel(
    const float* __restrict__ m_ws, const float* __restrict__ l_ws,
    const float* __restrict__ ck_ws, float* __restrict__ ctx,
    float* __restrict__ w /* raw scores in, weights out */) {
  const int b = blockIdx.x, tid = threadIdx.x;
  __shared__ float msh[NSTRIP], lsh[NSTRIP];
  if (tid < NSTRIP) {
    msh[tid] = m_ws[b * NSTRIP + tid];
    lsh[tid] = l_ws[b * NSTRIP + tid];
  }
  __syncthreads();
  float M = msh[0];
#pragma unroll
  for (int k = 1; k < NSTRIP; k++) M = fmaxf(M, msh[k]);
  float L = 0.f;
#pragma unroll
  for (int k = 0; k < NSTRIP; k++) L += lsh[k] * __expf(msh[k] - M);
  const float invL = 1.f / L;

  float2 acc = {0.f, 0.f};
#pragma unroll
  for (int k = 0; k < NSTRIP; k++) {
    float sc = __expf(msh[k] - M);
    float2 t = *(const float2*)&ck_ws[((size_t)(b * NSTRIP + k)) * 512 + tid * 2];
    acc.x += sc * t.x; acc.y += sc * t.y;
  }
  acc.x *= invL; acc.y *= invL;
  *(float2*)&ctx[(b << 9) + tid * 2] = acc;

  float* row = w + (size_t)b * NS;
#pragma unroll
  for (int i = 0; i < 8; i++) {
    float s = row[i * 256 + tid];
    row[i * 256 + tid] = __expf(s - M) * invL;
  }
}

extern "C" void kernel_launch(void* const* d_in, const int* in_sizes, int n_in,
                              void* d_out, int out_size, void* d_ws, size_t ws_size,
                              hipStream_t stream) {
  (void)in_sizes; (void)n_in; (void)out_size; (void)ws_size;
  const float* H  = (const float*)d_in[0];
  const float* EO = (const float*)d_in[1];
  const float* W1 = (const float*)d_in[2];
  const float* b1 = (const float*)d_in[3];
  const float* W2 = (const float*)d_in[4];
  const float* b2 = (const float*)d_in[5];
  const float* V  = (const float*)d_in[6];
  // d_in[7] = bv: softmax is shift-invariant -> unused.

  float* out_ctx = (float*)d_out;            // [64*512]
  float* out_w   = (float*)d_out + NB * NE;  // [64*2048] raw scores -> weights

  char* ws = (char*)d_ws;
  unsigned short* W1p = (unsigned short*)ws;            // 512 KB
  float* cvec = (float*)(ws + 512 * 1024);              // 128 KB
  float* m_ws = (float*)(ws + 640 * 1024);              // 8 KB
  float* l_ws = (float*)(ws + 656 * 1024);              // 8 KB
  float* ck_ws = (float*)(ws + 672 * 1024);             // 4 MB

  pack_w1_kernel<<<1024, 256, 0, stream>>>(W1, W1p);
  compute_c_kernel<<<NB, 512, 0, stream>>>(H, W2, b1, b2, cvec);
  scores_ctx_kernel<<<NB * NSTRIP, 512, 0, stream>>>(EO, W1p, cvec, V, out_w,
                                                     m_ws, l_ws, ck_ws);
  combine_kernel<<<NB, 256, 0, stream>>>(m_ws, l_ws, ck_ws, out_ctx, out_w);
}